// Round 4
// baseline (21.132 us; speedup 1.0000x reference)
//
#include <hip/hip_runtime.h>

// Reference reduces exactly to mean(where(up < 0.2, up, 0)):
// the scatter-min writes strictly-positive values (110-i)/50, i<110, into a
// ZERO-initialized buffer -> right2up == 0 identically, pixel_diff = |up|,
// masked mean over all elements. Only d_in[0] (up) is read.
//
// SINGLE kernel, single graph node. Fence-free mailbox finalize:
//  - block i publishes its float partial via atomicExch of (MAGIC<<32|bits)
//    to its OWN slot (distinct addresses -> no contention, no fences;
//    round-2 showed __threadfence+shared counter costs ~100us).
//  - block 0 (first dispatched -> resident from t=0, no deadlock) polls all
//    slots via atomicAdd(slot,0) until MAGIC seen, sums payloads in FIXED
//    index order (bit-deterministic), writes out, resets slots to 0.
//  - 0xAA poison top32 != MAGIC -> poisoned ws can never fake a partial.

#define RED_BLOCKS 2048
#define RED_THREADS 256
#define NT (RED_BLOCKS * RED_THREADS)     // 524,288 threads
#define SLOTS_PER_THREAD (RED_BLOCKS / RED_THREADS)  // 8
#define MAGIC_HI 0x5A17C0DEu

__device__ __forceinline__ float mask_sum4(float4 v) {
    float x = fabsf(v.x), y = fabsf(v.y), z = fabsf(v.z), w = fabsf(v.w);
    return ((x < 0.2f) ? x : 0.f) + ((y < 0.2f) ? y : 0.f)
         + ((z < 0.2f) ? z : 0.f) + ((w < 0.2f) ? w : 0.f);
}

__global__ __launch_bounds__(RED_THREADS)
void closs_onepass_kernel(const float* __restrict__ up, float* __restrict__ out,
                          unsigned long long* __restrict__ slots,
                          int n4, float inv_n) {
    const float4* __restrict__ up4 = reinterpret_cast<const float4*>(up);
    const int tid = blockIdx.x * blockDim.x + threadIdx.x;

    float a0 = 0.f, a1 = 0.f, a2 = 0.f, a3 = 0.f;
    if (n4 == 8 * NT) {
        // exact fit: 8 float4/thread, 4 independent loads in flight per group
        #pragma unroll
        for (int it = 0; it < 2; ++it) {
            float4 v0 = up4[tid + (it * 4 + 0) * NT];
            float4 v1 = up4[tid + (it * 4 + 1) * NT];
            float4 v2 = up4[tid + (it * 4 + 2) * NT];
            float4 v3 = up4[tid + (it * 4 + 3) * NT];
            a0 += mask_sum4(v0); a1 += mask_sum4(v1);
            a2 += mask_sum4(v2); a3 += mask_sum4(v3);
        }
    } else {
        for (int idx = tid; idx < n4; idx += NT) a0 += mask_sum4(up4[idx]);
    }
    float acc = (a0 + a1) + (a2 + a3);

    #pragma unroll
    for (int off = 32; off > 0; off >>= 1) acc += __shfl_down(acc, off, 64);
    __shared__ float sdata[RED_THREADS / 64];
    const int lane = threadIdx.x & 63, wid = threadIdx.x >> 6;
    if (lane == 0) sdata[wid] = acc;
    __syncthreads();

    if (threadIdx.x == 0) {
        float s = (sdata[0] + sdata[1]) + (sdata[2] + sdata[3]);
        unsigned long long payload =
            ((unsigned long long)MAGIC_HI << 32) | (unsigned long long)__float_as_uint(s);
        atomicExch(&slots[blockIdx.x], payload);   // device-scope publish, own address
    }

    if (blockIdx.x == 0) {
        __syncthreads();   // sdata reuse + block-uniform barrier
        const int base = threadIdx.x * SLOTS_PER_THREAD;
        float vals[SLOTS_PER_THREAD];
        unsigned ready = 0;
        while (ready != (1u << SLOTS_PER_THREAD) - 1u) {
            #pragma unroll
            for (int k = 0; k < SLOTS_PER_THREAD; ++k) {
                if (!(ready & (1u << k))) {
                    unsigned long long v = atomicAdd(&slots[base + k], 0ull);
                    if ((unsigned)(v >> 32) == MAGIC_HI) {
                        vals[k] = __uint_as_float((unsigned)(v & 0xFFFFFFFFull));
                        ready |= 1u << k;
                    }
                }
            }
        }
        // fixed-order deterministic final sum
        float f = ((vals[0] + vals[1]) + (vals[2] + vals[3]))
                + ((vals[4] + vals[5]) + (vals[6] + vals[7]));
        #pragma unroll
        for (int off = 32; off > 0; off >>= 1) f += __shfl_down(f, off, 64);
        if (lane == 0) sdata[wid] = f;
        __syncthreads();
        if (threadIdx.x == 0)
            out[0] = ((sdata[0] + sdata[1]) + (sdata[2] + sdata[3])) * inv_n;
        // reset own slots for the next call (each thread owns its 8 slots)
        #pragma unroll
        for (int k = 0; k < SLOTS_PER_THREAD; ++k)
            atomicExch(&slots[base + k], 0ull);
    }
}

extern "C" void kernel_launch(void* const* d_in, const int* in_sizes, int n_in,
                              void* d_out, int out_size, void* d_ws, size_t ws_size,
                              hipStream_t stream) {
    const float* up = (const float*)d_in[0];
    float* out = (float*)d_out;
    unsigned long long* slots = (unsigned long long*)d_ws;  // 2048 * 8 B = 16 KiB

    const int n  = in_sizes[0];   // 64*1*512*512 = 16,777,216
    const int n4 = n >> 2;
    const float inv_n = 1.0f / (float)n;

    closs_onepass_kernel<<<RED_BLOCKS, RED_THREADS, 0, stream>>>(up, out, slots, n4, inv_n);
}